// Round 2
// baseline (717.755 us; speedup 1.0000x reference)
//
#include <hip/hip_runtime.h>

// B=1024, A=256, E=4, M1=128, M2=16, H1=32, H2=64
#define XROW   1537          // 6*A + 1 floats per x row
#define NTHR   256

// Per-thread MLP + g-streaming (8 phases x 16 m) + wave-local P partials.
// 'e' may be SGPR-uniform (scalar weight loads) or per-lane (mixed wave).
__device__ __forceinline__ void process_tile(
    int e, float v, int w, int lane,
    const float* __restrict__ W1, const float* __restrict__ b1,
    const float* __restrict__ W2, const float* __restrict__ b2,
    const float* __restrict__ W3, const float* __restrict__ b3,
    float (*g_l)[64][17],         // [wave][a_local][m_local]
    const float (*Rm4)[4],        // [compact a][c], mask folded
    float (*Pw)[128][4])          // [wave][m][c] partials
{
    // ---- h2 = relu(W2^T relu(v*W1 + b1) + b2), h2 in registers ----
    float h2[64];
    const float* b2e = b2 + e * 64;
    #pragma unroll
    for (int o = 0; o < 64; ++o) h2[o] = b2e[o];

    const float* W1e = W1 + e * 32;
    const float* b1e = b1 + e * 32;
    const float* W2e = W2 + e * 2048;
    for (int i = 0; i < 32; ++i) {
        float h1i = fmaxf(fmaf(v, W1e[i], b1e[i]), 0.f);
        const float* w2row = W2e + i * 64;
        #pragma unroll
        for (int o = 0; o < 64; ++o) h2[o] = fmaf(h1i, w2row[o], h2[o]);
    }
    #pragma unroll
    for (int o = 0; o < 64; ++o) h2[o] = fmaxf(h2[o], 0.f);

    // ---- stream g in 8 phases of 16 m; wave-local transposed P phase ----
    const float* W3e = W3 + e * 8192;
    const float* b3e = b3 + e * 128;
    const int m_loc = lane & 15;
    const int qtr   = lane >> 4;

    for (int ph = 0; ph < 8; ++ph) {
        float g16[16];
        #pragma unroll
        for (int j = 0; j < 16; ++j) g16[j] = b3e[ph * 16 + j];
        #pragma unroll
        for (int i = 0; i < 64; ++i) {
            const float* w3row = W3e + i * 128 + ph * 16;
            float h = h2[i];
            #pragma unroll
            for (int j = 0; j < 16; ++j) g16[j] = fmaf(h, w3row[j], g16[j]);
        }
        #pragma unroll
        for (int j = 0; j < 16; ++j) g_l[w][lane][j] = g16[j];
        // single drain: writes visible before reads (also orders vs compiler)
        asm volatile("s_waitcnt lgkmcnt(0)" ::: "memory");

        // P phase: lane = (m_loc, qtr); qtr sums 16 a's, then combine
        float a0 = 0.f, a1 = 0.f, a2 = 0.f, a3 = 0.f;
        #pragma unroll
        for (int k = 0; k < 16; ++k) {
            int a = qtr * 16 + k;
            float g = g_l[w][a][m_loc];
            const float4 r = *(const float4*)&Rm4[w * 64 + a][0];
            a0 = fmaf(g, r.x, a0);
            a1 = fmaf(g, r.y, a1);
            a2 = fmaf(g, r.z, a2);
            a3 = fmaf(g, r.w, a3);
        }
        a0 += __shfl_xor(a0, 16);  a1 += __shfl_xor(a1, 16);
        a2 += __shfl_xor(a2, 16);  a3 += __shfl_xor(a3, 16);
        a0 += __shfl_xor(a0, 32);  a1 += __shfl_xor(a1, 32);
        a2 += __shfl_xor(a2, 32);  a3 += __shfl_xor(a3, 32);
        if (qtr == 0) {
            float4 p; p.x = a0; p.y = a1; p.z = a2; p.w = a3;
            *(float4*)&Pw[w][ph * 16 + m_loc][0] = p;
        }
        // compiler-order barrier only: same-wave DS ops execute in order,
        // so next phase's ds_writes cannot overtake this phase's ds_reads.
        asm volatile("" ::: "memory");
    }
}

__global__ void __launch_bounds__(NTHR, 4)
be_kernel(const float* __restrict__ x,
          const float* __restrict__ W1, const float* __restrict__ b1,
          const float* __restrict__ W2, const float* __restrict__ b2,
          const float* __restrict__ W3, const float* __restrict__ b3,
          float* __restrict__ out)
{
    __shared__ float g_l[4][64][17];    // 17408 B, per-wave g tile (odd stride)
    __shared__ float Rm4[256][4];       // 4096 B, R^T mask-folded, [compact a][c]
    __shared__ float vca[256];          // compacted v
    __shared__ int   eca[256];          // compacted expert
    __shared__ float Pw[4][128][4];     // 8192 B, per-wave P partials
    __shared__ float Pr[128][4];        // 2048 B, reduced P
    __shared__ int   cntw[4][4];        // [wave][expert] counts

    const int tid  = threadIdx.x;
    const int b    = blockIdx.x;
    const int lane = tid & 63;
    const int w    = tid >> 6;
    const long xb  = (long)b * XROW;

    // ---- load this thread's (a = tid) element ----
    float v  = x[xb + 2 * tid];
    float tf = x[xb + 2 * tid + 1];
    int e = (int)tf;
    e = max(0, min(3, e));
    int N = (int)x[xb + 1536];
    float maskf = (tid < N) ? 1.f : 0.f;

    // ---- deterministic expert compaction via ballots ----
    unsigned long long mybal = 0ull;
    #pragma unroll
    for (int q = 0; q < 4; ++q) {
        unsigned long long bq = __ballot(e == q);
        if (lane == 0) cntw[w][q] = __popcll(bq);
        if (e == q) mybal = bq;
    }
    int rank = __popcll(mybal & ((1ull << lane) - 1ull));
    __syncthreads();

    int off = 0;
    #pragma unroll
    for (int q = 0; q < 4; ++q) {
        #pragma unroll
        for (int w2 = 0; w2 < 4; ++w2) {
            int cw = cntw[w2][q];
            if (q < e || (q == e && w2 < w)) off += cw;
        }
    }
    const int ci = off + rank;             // my compact slot in [0,256)
    vca[ci] = v;
    eca[ci] = e;
    {
        float4 rv;
        rv.x = x[xb + 512 + 4 * tid + 0] * maskf;
        rv.y = x[xb + 512 + 4 * tid + 1] * maskf;
        rv.z = x[xb + 512 + 4 * tid + 2] * maskf;
        rv.w = x[xb + 512 + 4 * tid + 3] * maskf;
        *(float4*)&Rm4[ci][0] = rv;
    }
    __syncthreads();

    // ---- process compact slot 'tid' ----
    float v2 = vca[tid];
    int   e2 = eca[tid];
    int   ef = __builtin_amdgcn_readfirstlane(e2);
    if (__ballot(e2 != ef) == 0ull) {
        process_tile(ef, v2, w, lane, W1, b1, W2, b2, W3, b3, g_l, Rm4, Pw);
    } else {
        process_tile(e2, v2, w, lane, W1, b1, W2, b2, W3, b3, g_l, Rm4, Pw);
    }
    __syncthreads();

    // ---- reduce P over waves (deterministic order) ----
    #pragma unroll
    for (int r = 0; r < 2; ++r) {
        int idx = r * 256 + tid;           // over 512 = 128 m * 4 c
        int m = idx >> 2, c = idx & 3;
        Pr[m][c] = (Pw[0][m][c] + Pw[1][m][c]) + (Pw[2][m][c] + Pw[3][m][c]);
    }
    __syncthreads();

    // ---- D[m][n] = sum_c P[m][c] * P[n][c]  (Q == P[:16,:]^T) ----
    float* outb = out + (long)b * 2048;
    #pragma unroll
    for (int r = 0; r < 8; ++r) {
        int o = r * 256 + tid;
        int m = o >> 4, n = o & 15;
        float d = 0.f;
        #pragma unroll
        for (int c = 0; c < 4; ++c)
            d = fmaf(Pr[m][c], Pr[n][c], d);
        outb[o] = d;
    }
}

extern "C" void kernel_launch(void* const* d_in, const int* in_sizes, int n_in,
                              void* d_out, int out_size, void* d_ws, size_t ws_size,
                              hipStream_t stream)
{
    const float* x  = (const float*)d_in[0];
    const float* W1 = (const float*)d_in[1];
    const float* b1 = (const float*)d_in[2];
    const float* W2 = (const float*)d_in[3];
    const float* b2 = (const float*)d_in[4];
    const float* W3 = (const float*)d_in[5];
    const float* b3 = (const float*)d_in[6];
    float* out = (float*)d_out;

    be_kernel<<<1024, NTHR, 0, stream>>>(x, W1, b1, W2, b2, W3, b3, out);
}

// Round 3
// 416.516 us; speedup vs baseline: 1.7232x; 1.7232x over previous
//
#include <hip/hip_runtime.h>

// B=1024, A=256, E=4, M1=128, M2=16, H1=32, H2=64
#define XROW 1537
#define NTHR 256

__global__ void __launch_bounds__(NTHR)
be_kernel(const float* __restrict__ x,
          const float* __restrict__ W1, const float* __restrict__ b1,
          const float* __restrict__ W2, const float* __restrict__ b2,
          const float* __restrict__ W3, const float* __restrict__ b3,
          float* __restrict__ out)
{
    __shared__ __align__(16) float g_l[4][8][68];   // per-wave g chunk [m][a]
    __shared__ float RmT[4][324];     // [c][slot], mask folded, tail zeroed
    __shared__ float vca[256];        // compacted v
    __shared__ float Pw[4][128][4];   // per-wave P partials
    __shared__ float Pr[128][4];      // reduced P
    __shared__ int   cntw[4][4];      // [wave][expert] counts
    __shared__ int   ckq[8], cks[8], ckl[8];  // chunk expert / start / len
    __shared__ int   nck;

    const int tid  = threadIdx.x;
    const int b    = blockIdx.x;
    const int lane = tid & 63;
    const int w    = tid >> 6;
    const long xb  = (long)b * XROW;

    // ---- load this thread's (a = tid) element ----
    float v  = x[xb + 2 * tid];
    int e = (int)x[xb + 2 * tid + 1];
    e = max(0, min(3, e));
    int N = (int)x[xb + 1536];
    float maskf = (tid < N) ? 1.f : 0.f;

    // ---- deterministic expert compaction via ballots ----
    unsigned long long mybal = 0ull;
    #pragma unroll
    for (int q = 0; q < 4; ++q) {
        unsigned long long bq = __ballot(e == q);
        if (lane == 0) cntw[w][q] = __popcll(bq);
        if (e == q) mybal = bq;
    }
    int rank = __popcll(mybal & ((1ull << lane) - 1ull));
    __syncthreads();

    int off = 0;
    #pragma unroll
    for (int q = 0; q < 4; ++q)
        #pragma unroll
        for (int w2 = 0; w2 < 4; ++w2) {
            int cw = cntw[w2][q];
            if (q < e || (q == e && w2 < w)) off += cw;
        }
    const int ci = off + rank;             // compact slot, sorted by expert
    vca[ci] = v;
    #pragma unroll
    for (int c = 0; c < 4; ++c)
        RmT[c][ci] = x[xb + 512 + 4 * tid + c] * maskf;
    if (tid < 68) {                        // zero pad tail (avoid NaN garbage)
        #pragma unroll
        for (int c = 0; c < 4; ++c) RmT[c][256 + tid] = 0.f;
    }

    // ---- chunk list: (expert, start, len<=64), experts contiguous ----
    if (tid == 0) {
        int base = 0, n = 0;
        for (int q = 0; q < 4; ++q) {
            int cq = cntw[0][q] + cntw[1][q] + cntw[2][q] + cntw[3][q];
            for (int t = 0; t < cq; t += 64) {
                ckq[n] = q; cks[n] = base + t; ckl[n] = min(64, cq - t); ++n;
            }
            base += cq;
        }
        nck = n;
    }

    // zero my wave's Pw (own region only; in-order DS within wave)
    #pragma unroll
    for (int r = 0; r < 8; ++r)
        ((float*)Pw[w])[r * 64 + lane] = 0.f;

    __syncthreads();

    const int m_loc = lane >> 3;
    const int cc    = (lane >> 1) & 3;
    const int half  = lane & 1;
    const int NC    = nck;

    // ---- chunks round-robin over waves; every chunk is expert-uniform ----
    for (int ji = w; ji < NC; ji += 4) {
        int e_v = ckq[ji];                              // VGPR (vmcnt loads)
        int e_s = __builtin_amdgcn_readfirstlane(e_v);  // SGPR (s_loads)
        int start = cks[ji];
        int len   = ckl[ji];
        bool valid = lane < len;
        float va = valid ? vca[start + lane] : 0.f;

        // ---- h2 = relu(W2^T relu(va*W1 + b1) + b2); scalar weights ----
        float h2[64];
        const float* b2e = b2 + e_s * 64;
        #pragma unroll
        for (int o = 0; o < 64; ++o) h2[o] = b2e[o];
        const float* W1e = W1 + e_s * 32;
        const float* b1e = b1 + e_s * 32;
        const float* W2e = W2 + e_s * 2048;
        for (int i = 0; i < 32; ++i) {
            float h1i = fmaxf(fmaf(va, W1e[i], b1e[i]), 0.f);
            const float* w2r = W2e + i * 64;
            #pragma unroll
            for (int o = 0; o < 64; ++o) h2[o] = fmaf(h1i, w2r[o], h2[o]);
        }
        #pragma unroll
        for (int o = 0; o < 64; ++o) h2[o] = fmaxf(h2[o], 0.f);

        // ---- g in 16 chunks of 8 m; W3/b3 via vmcnt (uniform-addr vector) ----
        const float* W3e = W3 + e_v * 8192;
        const float* b3e = b3 + e_v * 128;

        for (int mb = 0; mb < 16; ++mb) {
            float g8[8];
            float4 bl0 = *(const float4*)(b3e + mb * 8);
            float4 bl1 = *(const float4*)(b3e + mb * 8 + 4);
            g8[0]=bl0.x; g8[1]=bl0.y; g8[2]=bl0.z; g8[3]=bl0.w;
            g8[4]=bl1.x; g8[5]=bl1.y; g8[6]=bl1.z; g8[7]=bl1.w;
            #pragma unroll
            for (int i = 0; i < 64; ++i) {
                const float* w3r = W3e + i * 128 + mb * 8;
                float4 wa = *(const float4*)w3r;
                float4 wb = *(const float4*)(w3r + 4);
                float h = h2[i];
                g8[0]=fmaf(h,wa.x,g8[0]); g8[1]=fmaf(h,wa.y,g8[1]);
                g8[2]=fmaf(h,wa.z,g8[2]); g8[3]=fmaf(h,wa.w,g8[3]);
                g8[4]=fmaf(h,wb.x,g8[4]); g8[5]=fmaf(h,wb.y,g8[5]);
                g8[6]=fmaf(h,wb.z,g8[6]); g8[7]=fmaf(h,wb.w,g8[7]);
            }
            // invalid lanes write 0 so cross-chunk R reads contribute nothing
            #pragma unroll
            for (int j = 0; j < 8; ++j) g_l[w][j][lane] = valid ? g8[j] : 0.f;
            // no asm drain: same-wave DS ops are in-order; compiler inserts
            // the counted lgkmcnt before use of the reads below.

            float acc = 0.f;
            #pragma unroll
            for (int k = 0; k < 8; ++k) {
                int ai = half * 32 + 4 * k;
                float4 gv = *(const float4*)&g_l[w][m_loc][ai];   // 16B aligned
                // RmT reads scalar: chunk start not 16B-aligned
                float r0 = RmT[cc][start + ai + 0];
                float r1 = RmT[cc][start + ai + 1];
                float r2 = RmT[cc][start + ai + 2];
                float r3 = RmT[cc][start + ai + 3];
                acc = fmaf(gv.x, r0, acc);
                acc = fmaf(gv.y, r1, acc);
                acc = fmaf(gv.z, r2, acc);
                acc = fmaf(gv.w, r3, acc);
            }
            acc += __shfl_xor(acc, 1);          // combine halves
            if (half == 0) Pw[w][mb * 8 + m_loc][cc] += acc;  // unique-lane RMW
        }
    }
    __syncthreads();

    // ---- reduce P over waves (deterministic order) ----
    #pragma unroll
    for (int r = 0; r < 2; ++r) {
        int idx = r * 256 + tid;               // 512 = 128 m * 4 c
        int m = idx >> 2, c = idx & 3;
        Pr[m][c] = (Pw[0][m][c] + Pw[1][m][c]) + (Pw[2][m][c] + Pw[3][m][c]);
    }
    __syncthreads();

    // ---- D[m][n] = sum_c P[m][c] * P[n][c]  (Q == P[:16,:]^T) ----
    float* outb = out + (long)b * 2048;
    #pragma unroll
    for (int r = 0; r < 8; ++r) {
        int o = r * 256 + tid;
        int m = o >> 4, n = o & 15;
        float d = 0.f;
        #pragma unroll
        for (int c = 0; c < 4; ++c)
            d = fmaf(Pr[m][c], Pr[n][c], d);
        outb[o] = d;
    }
}

extern "C" void kernel_launch(void* const* d_in, const int* in_sizes, int n_in,
                              void* d_out, int out_size, void* d_ws, size_t ws_size,
                              hipStream_t stream)
{
    const float* x  = (const float*)d_in[0];
    const float* W1 = (const float*)d_in[1];
    const float* b1 = (const float*)d_in[2];
    const float* W2 = (const float*)d_in[3];
    const float* b2 = (const float*)d_in[4];
    const float* W3 = (const float*)d_in[5];
    const float* b3 = (const float*)d_in[6];
    float* out = (float*)d_out;

    be_kernel<<<1024, NTHR, 0, stream>>>(x, W1, b1, W2, b2, W3, b3, out);
}

// Round 4
// 77.628 us; speedup vs baseline: 9.2461x; 5.3656x over previous
//
#include <hip/hip_runtime.h>

// B=1024, A=256, E=4, M1=128, M2=16, H1=32, H2=64
#define XROW 1537
#define NTHR 256

__global__ void __launch_bounds__(NTHR)
be_kernel(const float* __restrict__ x,
          const float* __restrict__ W1, const float* __restrict__ b1,
          const float* __restrict__ W2, const float* __restrict__ b2,
          const float* __restrict__ W3, const float* __restrict__ b3,
          float* __restrict__ out)
{
    __shared__ float vca[272];                      // compacted v (pads = 0)
    __shared__ __align__(16) float RmT[4][272];     // [c][slot], mask folded, pads 0
    __shared__ __align__(16) float H2T[64][68];     // [i][a_local], tile of h2
    __shared__ __align__(16) float S_l[4][4][64];   // [e][c][i]
    __shared__ float Tpart[4][4][16];
    __shared__ float T16[16];                       // T[e][c]
    __shared__ float Pr5[128 * 5];                  // P padded stride 5
    __shared__ int   cntw[4][4];                    // [wave][expert]

    const int tid  = threadIdx.x;
    const int b    = blockIdx.x;
    const int lane = tid & 63;
    const int w    = tid >> 6;
    const long xb  = (long)b * XROW;

    // ---- per-a input ----
    float v = x[xb + 2 * tid];
    int e = (int)x[xb + 2 * tid + 1];
    e = max(0, min(3, e));
    int N = (int)x[xb + 1536];
    float maskf = (tid < N) ? 1.f : 0.f;

    // ---- ballot compaction (deterministic ranks) ----
    unsigned long long mybal = 0ull;
    #pragma unroll
    for (int q = 0; q < 4; ++q) {
        unsigned long long bq = __ballot(e == q);
        if (lane == 0) cntw[w][q] = __popcll(bq);
        if (e == q) mybal = bq;
    }
    int rank = __popcll(mybal & ((1ull << lane) - 1ull));

    // zero pads (whole arrays) before scatter
    for (int idx = tid; idx < 272; idx += NTHR) vca[idx] = 0.f;
    for (int idx = tid; idx < 4 * 272; idx += NTHR) (&RmT[0][0])[idx] = 0.f;
    __syncthreads();

    // block counts -> 4-aligned expert bases
    int c0 = cntw[0][0] + cntw[1][0] + cntw[2][0] + cntw[3][0];
    int c1 = cntw[0][1] + cntw[1][1] + cntw[2][1] + cntw[3][1];
    int c2_ = cntw[0][2] + cntw[1][2] + cntw[2][2] + cntw[3][2];
    int c3 = cntw[0][3] + cntw[1][3] + cntw[2][3] + cntw[3][3];
    const int B0 = 0;
    const int B1 = (B0 + c0 + 3) & ~3;
    const int B2 = (B1 + c1 + 3) & ~3;
    const int B3 = (B2 + c2_ + 3) & ~3;
    const int St4 = (B3 + c3 + 3) & ~3;             // <= 268

    int offw = 0;
    #pragma unroll
    for (int w2 = 0; w2 < 4; ++w2) if (w2 < w) offw += cntw[w2][e];
    int Bsel = (e == 0) ? B0 : ((e == 1) ? B1 : ((e == 2) ? B2 : B3));
    int ci = Bsel + offw + rank;

    vca[ci] = v;
    #pragma unroll
    for (int c = 0; c < 4; ++c)
        RmT[c][ci] = x[xb + 512 + 4 * tid + c] * maskf;
    __syncthreads();

    // ---- T[e][c] = sum_a R_masked (distributed partials) ----
    {
        int te = tid >> 6, tc = (tid >> 4) & 3, tk = tid & 15;
        int s0 = (te == 0) ? B0 : ((te == 1) ? B1 : ((te == 2) ? B2 : B3));
        int s1 = (te == 0) ? B1 : ((te == 1) ? B2 : ((te == 2) ? B3 : St4));
        float ts = 0.f;
        for (int s = s0 + tk; s < s1; s += 16) ts += RmT[tc][s];
        Tpart[te][tc][tk] = ts;
    }
    __syncthreads();
    if (tid < 16) {
        float t = 0.f;
        #pragma unroll
        for (int k = 0; k < 16; ++k) t += Tpart[tid >> 2][tid & 3][k];
        T16[tid] = t;
    }   // ordered before phase-3 reads by tile-loop barriers

    // ---- tiles of 64 a: 2a h2 -> H2T, 2b S accumulation ----
    float S4_0 = 0.f, S4_1 = 0.f, S4_2 = 0.f, S4_3 = 0.f;
    const int ntiles = (St4 + 63) >> 6;
    const int i2 = tid >> 2, cc = tid & 3;

    for (int t = 0; t < ntiles; ++t) {
        const int t64 = t << 6;
        // --- 2a: wave w computes a in [t64+16w, t64+16w+16) ---
        int a = t64 + (w << 4);
        int aend = min(a + 16, St4);
        while (a < aend) {
            int ev = (a >= B1) + (a >= B2) + (a >= B3);
            int rend = (ev == 0) ? B1 : ((ev == 1) ? B2 : ((ev == 2) ? B3 : St4));
            rend = min(rend, aend);
            int es = __builtin_amdgcn_readfirstlane(ev);
            const float* W1e = W1 + es * 32;
            const float* b1e = b1 + es * 32;
            const float* W2e = W2 + es * 2048 + lane;
            float W1r[32], b1r[32], W2c[32];
            #pragma unroll
            for (int j = 0; j < 32; ++j) {
                W1r[j] = W1e[j];
                b1r[j] = b1e[j];
                W2c[j] = W2e[j * 64];
            }
            float b2s = b2[es * 64 + lane];
            for (; a < rend; ++a) {
                float va = vca[a];               // broadcast read
                float acc = b2s;
                #pragma unroll
                for (int j = 0; j < 32; ++j) {
                    float h = fmaxf(fmaf(va, W1r[j], b1r[j]), 0.f);
                    acc = fmaf(h, W2c[j], acc);
                }
                H2T[lane][a - t64] = fmaxf(acc, 0.f);
            }
        }
        __syncthreads();
        // --- 2b: thread (i2, cc) accumulates S over this tile ---
        #define SEG(Sreg, LO, HI)                                           \
        {                                                                   \
            int s = max(LO, t64), sE = min(HI, t64 + 64);                   \
            for (; s < sE; s += 4) {                                        \
                const float4 h4 = *(const float4*)&H2T[i2][s - t64];        \
                const float4 r4 = *(const float4*)&RmT[cc][s];              \
                Sreg = fmaf(h4.x, r4.x, Sreg); Sreg = fmaf(h4.y, r4.y, Sreg);\
                Sreg = fmaf(h4.z, r4.z, Sreg); Sreg = fmaf(h4.w, r4.w, Sreg);\
            }                                                               \
        }
        SEG(S4_0, B0, B1)
        SEG(S4_1, B1, B2)
        SEG(S4_2, B2, B3)
        SEG(S4_3, B3, St4)
        #undef SEG
        __syncthreads();
    }

    // ---- write S ----
    S_l[0][cc][i2] = S4_0;
    S_l[1][cc][i2] = S4_1;
    S_l[2][cc][i2] = S4_2;
    S_l[3][cc][i2] = S4_3;
    __syncthreads();

    // ---- phase 3: P[m][c] = sum_{e,i} W3[e,i,m] S[e,i,c] + sum_e b3[e,m] T[e,c]
    {
        const int m = tid & 127;
        const int cp = tid >> 7;                 // c pair {2cp, 2cp+1}
        float acc0 = 0.f, acc1 = 0.f;
        #pragma unroll
        for (int ee = 0; ee < 4; ++ee) {
            const float* W3e = W3 + ee * 8192 + m;
            #pragma unroll 4
            for (int i4 = 0; i4 < 16; ++i4) {
                const float4 sA = *(const float4*)&S_l[ee][2 * cp][4 * i4];
                const float4 sB = *(const float4*)&S_l[ee][2 * cp + 1][4 * i4];
                const float* wp = W3e + (i4 * 4) * 128;
                float w0 = wp[0], w1 = wp[128], w2 = wp[256], w3 = wp[384];
                acc0 = fmaf(w0, sA.x, acc0); acc0 = fmaf(w1, sA.y, acc0);
                acc0 = fmaf(w2, sA.z, acc0); acc0 = fmaf(w3, sA.w, acc0);
                acc1 = fmaf(w0, sB.x, acc1); acc1 = fmaf(w1, sB.y, acc1);
                acc1 = fmaf(w2, sB.z, acc1); acc1 = fmaf(w3, sB.w, acc1);
            }
            float b3v = b3[ee * 128 + m];
            acc0 = fmaf(b3v, T16[ee * 4 + 2 * cp], acc0);
            acc1 = fmaf(b3v, T16[ee * 4 + 2 * cp + 1], acc1);
        }
        Pr5[m * 5 + 2 * cp]     = acc0;
        Pr5[m * 5 + 2 * cp + 1] = acc1;
    }
    __syncthreads();

    // ---- D[m][n] = sum_c P[m][c] P[n][c] ----
    float* outb = out + (long)b * 2048;
    #pragma unroll
    for (int r = 0; r < 8; ++r) {
        int o = r * 256 + tid;
        int m = o >> 4, n = o & 15;
        float d = 0.f;
        #pragma unroll
        for (int c = 0; c < 4; ++c)
            d = fmaf(Pr5[m * 5 + c], Pr5[n * 5 + c], d);
        outb[o] = d;
    }
}

extern "C" void kernel_launch(void* const* d_in, const int* in_sizes, int n_in,
                              void* d_out, int out_size, void* d_ws, size_t ws_size,
                              hipStream_t stream)
{
    const float* x  = (const float*)d_in[0];
    const float* W1 = (const float*)d_in[1];
    const float* b1 = (const float*)d_in[2];
    const float* W2 = (const float*)d_in[3];
    const float* b2 = (const float*)d_in[4];
    const float* W3 = (const float*)d_in[5];
    const float* b3 = (const float*)d_in[6];
    float* out = (float*)d_out;

    be_kernel<<<1024, NTHR, 0, stream>>>(x, W1, b1, W2, b2, W3, b3, out);
}

// Round 5
// 42.065 us; speedup vs baseline: 17.0632x; 1.8454x over previous
//
#include <hip/hip_runtime.h>

// B=1024, A=256, E=4, M1=128, M2=16, H1=32, H2=64
#define XROW 1537
#define NTHR 256

// ws layout (floats): [0,128) = Tsort[4][32] sorted thresholds per expert
//                     [128, 128+16896) = AC[e][k(33)][o(64)][2] (A,C) pairs
// h2_pre[o] = v*A_k[o] + C_k[o] on interval k — exact piecewise-affine
// collapse of  relu(v*W1+b1) @ W2 + b2  in the scalar v.

__global__ void __launch_bounds__(NTHR)
be_prep(const float* __restrict__ W1, const float* __restrict__ b1,
        const float* __restrict__ W2, const float* __restrict__ b2,
        float* __restrict__ ws)
{
    __shared__ float t_s[4][32], w1_s[4][32], b1_s[4][32];
    __shared__ int   sidx[4][32];
    const int w = threadIdx.x >> 6, lane = threadIdx.x & 63;
    const int e = w;                       // one expert per wave

    if (lane < 32) {
        float w1v = W1[e * 32 + lane];
        float b1v = b1[e * 32 + lane];
        w1_s[e][lane] = w1v;
        b1_s[e][lane] = b1v;
        t_s[e][lane] = (w1v != 0.f) ? (-b1v / w1v) : 3.4e38f;
    }
    __syncthreads();
    if (lane < 32) {
        float ti = t_s[e][lane];
        int rank = 0;
        for (int j = 0; j < 32; ++j) {
            float tj = t_s[e][j];
            rank += (tj < ti) || (tj == ti && j < lane);
        }
        sidx[e][rank] = lane;
        ws[e * 32 + rank] = ti;            // sorted thresholds
    }
    __syncthreads();

    // sweep intervals; lane = o
    float* AC = ws + 128;
    const int o = lane;
    float A = 0.f, C = b2[e * 64 + o];
    for (int i = 0; i < 32; ++i) {         // active set at v = -inf
        float w1v = w1_s[e][i], b1v = b1_s[e][i];
        if ((w1v < 0.f) || (w1v == 0.f && b1v > 0.f)) {
            float w2v = W2[(e * 32 + i) * 64 + o];
            A = fmaf(w1v, w2v, A);
            C = fmaf(b1v, w2v, C);
        }
    }
    AC[(e * 33 + 0) * 128 + 2 * o]     = A;
    AC[(e * 33 + 0) * 128 + 2 * o + 1] = C;
    for (int k = 1; k <= 32; ++k) {
        int i = sidx[e][k - 1];
        float w1v = w1_s[e][i], b1v = b1_s[e][i];
        float w2v = W2[(e * 32 + i) * 64 + o];
        if (w1v > 0.f)      { A += w1v * w2v; C += b1v * w2v; }  // turns on
        else if (w1v < 0.f) { A -= w1v * w2v; C -= b1v * w2v; }  // turns off
        AC[(e * 33 + k) * 128 + 2 * o]     = A;
        AC[(e * 33 + k) * 128 + 2 * o + 1] = C;
    }
}

__global__ void __launch_bounds__(NTHR)
be_kernel(const float* __restrict__ x,
          const float* __restrict__ W3, const float* __restrict__ b3,
          const float* __restrict__ wsr,
          float* __restrict__ out)
{
    __shared__ float vca[272];                      // compacted v (pads = 0)
    __shared__ __align__(16) float RmT[4][272];     // [c][slot], mask folded
    __shared__ __align__(16) float H2T[64][68];     // [i][a_local]
    __shared__ __align__(16) float S_l[4][4][64];   // [e][c][i]
    __shared__ float Tpart[4][4][16];
    __shared__ float T16[16];
    __shared__ float Pr5[128 * 5];
    __shared__ float Ts_l[128];                     // sorted thresholds
    __shared__ int   kea[272];                      // per-slot AC base offset
    __shared__ int   cntw[4][4];

    const int tid  = threadIdx.x;
    const int b    = blockIdx.x;
    const int lane = tid & 63;
    const int w    = tid >> 6;
    const long xb  = (long)b * XROW;
    const float* ACg = wsr + 128;

    // ---- per-a input ----
    float v = x[xb + 2 * tid];
    int e = (int)x[xb + 2 * tid + 1];
    e = max(0, min(3, e));
    int N = (int)x[xb + 1536];
    float maskf = (tid < N) ? 1.f : 0.f;

    if (tid < 128) Ts_l[tid] = wsr[tid];

    // ---- ballot compaction ----
    unsigned long long mybal = 0ull;
    #pragma unroll
    for (int q = 0; q < 4; ++q) {
        unsigned long long bq = __ballot(e == q);
        if (lane == 0) cntw[w][q] = __popcll(bq);
        if (e == q) mybal = bq;
    }
    int rank = __popcll(mybal & ((1ull << lane) - 1ull));

    for (int idx = tid; idx < 272; idx += NTHR) vca[idx] = 0.f;
    for (int idx = tid; idx < 4 * 272; idx += NTHR) (&RmT[0][0])[idx] = 0.f;
    __syncthreads();

    int c0 = cntw[0][0] + cntw[1][0] + cntw[2][0] + cntw[3][0];
    int c1 = cntw[0][1] + cntw[1][1] + cntw[2][1] + cntw[3][1];
    int c2_ = cntw[0][2] + cntw[1][2] + cntw[2][2] + cntw[3][2];
    int c3 = cntw[0][3] + cntw[1][3] + cntw[2][3] + cntw[3][3];
    const int B0 = 0;
    const int B1 = (B0 + c0 + 3) & ~3;
    const int B2 = (B1 + c1 + 3) & ~3;
    const int B3 = (B2 + c2_ + 3) & ~3;
    const int St4 = (B3 + c3 + 3) & ~3;             // <= 268

    int offw = 0;
    #pragma unroll
    for (int w2 = 0; w2 < 4; ++w2) if (w2 < w) offw += cntw[w2][e];
    int Bsel = (e == 0) ? B0 : ((e == 1) ? B1 : ((e == 2) ? B2 : B3));
    int ci = Bsel + offw + rank;

    vca[ci] = v;
    #pragma unroll
    for (int c = 0; c < 4; ++c)
        RmT[c][ci] = x[xb + 512 + 4 * tid + c] * maskf;
    __syncthreads();

    // ---- interval index per slot: kea[a] = (e*33+k)*128 ----
    for (int a2 = tid; a2 < St4; a2 += NTHR) {
        int ev = (a2 >= B1) + (a2 >= B2) + (a2 >= B3);
        float va = vca[a2];
        const float* Ts = &Ts_l[ev * 32];
        int k = 0;
        #pragma unroll
        for (int st = 32; st >= 1; st >>= 1)
            if (k + st <= 32 && Ts[k + st - 1] <= va) k += st;
        kea[a2] = (ev * 33 + k) * 128;
    }

    // ---- T[e][c] = sum_a R_masked ----
    {
        int te = tid >> 6, tc = (tid >> 4) & 3, tk = tid & 15;
        int s0 = (te == 0) ? B0 : ((te == 1) ? B1 : ((te == 2) ? B2 : B3));
        int s1 = (te == 0) ? B1 : ((te == 1) ? B2 : ((te == 2) ? B3 : St4));
        float ts = 0.f;
        for (int s = s0 + tk; s < s1; s += 16) ts += RmT[tc][s];
        Tpart[te][tc][tk] = ts;
    }
    __syncthreads();
    if (tid < 16) {
        float t = 0.f;
        #pragma unroll
        for (int k = 0; k < 16; ++k) t += Tpart[tid >> 2][tid & 3][k];
        T16[tid] = t;
    }   // read only after tile-loop barriers

    // ---- tiles: 2a table-lookup h2, 2b S accumulation ----
    float S4_0 = 0.f, S4_1 = 0.f, S4_2 = 0.f, S4_3 = 0.f;
    const int ntiles = (St4 + 63) >> 6;
    const int i2 = tid >> 2, cc = tid & 3;

    for (int t = 0; t < ntiles; ++t) {
        const int t64 = t << 6;
        int a = t64 + (w << 4);
        int aend = min(a + 16, St4);
        for (; a < aend; ++a) {
            float va = vca[a];
            const float2 ac = *(const float2*)&ACg[kea[a] + 2 * lane];
            H2T[lane][a - t64] = fmaxf(fmaf(va, ac.x, ac.y), 0.f);
        }
        __syncthreads();
        #define SEG(Sreg, LO, HI)                                           \
        {                                                                   \
            int s = max(LO, t64), sE = min(HI, t64 + 64);                   \
            for (; s < sE; s += 4) {                                        \
                const float4 h4 = *(const float4*)&H2T[i2][s - t64];        \
                const float4 r4 = *(const float4*)&RmT[cc][s];              \
                Sreg = fmaf(h4.x, r4.x, Sreg); Sreg = fmaf(h4.y, r4.y, Sreg);\
                Sreg = fmaf(h4.z, r4.z, Sreg); Sreg = fmaf(h4.w, r4.w, Sreg);\
            }                                                               \
        }
        SEG(S4_0, B0, B1)
        SEG(S4_1, B1, B2)
        SEG(S4_2, B2, B3)
        SEG(S4_3, B3, St4)
        #undef SEG
        __syncthreads();
    }

    S_l[0][cc][i2] = S4_0;
    S_l[1][cc][i2] = S4_1;
    S_l[2][cc][i2] = S4_2;
    S_l[3][cc][i2] = S4_3;
    __syncthreads();

    // ---- P[m][c] = sum_{e,i} W3[e,i,m] S[e,i,c] + sum_e b3[e,m] T[e,c] ----
    {
        const int m = tid & 127;
        const int cp = tid >> 7;
        float acc0 = 0.f, acc1 = 0.f;
        #pragma unroll
        for (int ee = 0; ee < 4; ++ee) {
            const float* W3e = W3 + ee * 8192 + m;
            #pragma unroll 4
            for (int i4 = 0; i4 < 16; ++i4) {
                const float4 sA = *(const float4*)&S_l[ee][2 * cp][4 * i4];
                const float4 sB = *(const float4*)&S_l[ee][2 * cp + 1][4 * i4];
                const float* wp = W3e + (i4 * 4) * 128;
                float w0 = wp[0], w1 = wp[128], w2 = wp[256], w3 = wp[384];
                acc0 = fmaf(w0, sA.x, acc0); acc0 = fmaf(w1, sA.y, acc0);
                acc0 = fmaf(w2, sA.z, acc0); acc0 = fmaf(w3, sA.w, acc0);
                acc1 = fmaf(w0, sB.x, acc1); acc1 = fmaf(w1, sB.y, acc1);
                acc1 = fmaf(w2, sB.z, acc1); acc1 = fmaf(w3, sB.w, acc1);
            }
            float b3v = b3[ee * 128 + m];
            acc0 = fmaf(b3v, T16[ee * 4 + 2 * cp], acc0);
            acc1 = fmaf(b3v, T16[ee * 4 + 2 * cp + 1], acc1);
        }
        Pr5[m * 5 + 2 * cp]     = acc0;
        Pr5[m * 5 + 2 * cp + 1] = acc1;
    }
    __syncthreads();

    // ---- D[m][n] = sum_c P[m][c] P[n][c]  (Q == P[:16,:]^T) ----
    float* outb = out + (long)b * 2048;
    #pragma unroll
    for (int r = 0; r < 8; ++r) {
        int o = r * 256 + tid;
        int m = o >> 4, n = o & 15;
        float d = 0.f;
        #pragma unroll
        for (int c = 0; c < 4; ++c)
            d = fmaf(Pr5[m * 5 + c], Pr5[n * 5 + c], d);
        outb[o] = d;
    }
}

extern "C" void kernel_launch(void* const* d_in, const int* in_sizes, int n_in,
                              void* d_out, int out_size, void* d_ws, size_t ws_size,
                              hipStream_t stream)
{
    const float* x  = (const float*)d_in[0];
    const float* W1 = (const float*)d_in[1];
    const float* b1 = (const float*)d_in[2];
    const float* W2 = (const float*)d_in[3];
    const float* b2 = (const float*)d_in[4];
    const float* W3 = (const float*)d_in[5];
    const float* b3 = (const float*)d_in[6];
    float* out = (float*)d_out;
    float* ws  = (float*)d_ws;       // needs 68096 bytes

    be_prep<<<1, NTHR, 0, stream>>>(W1, b1, W2, b2, ws);
    be_kernel<<<1024, NTHR, 0, stream>>>(x, W3, b3, ws, out);
}